// Round 1
// baseline (683.132 us; speedup 1.0000x reference)
//
#include <hip/hip_runtime.h>
#include <hip/hip_bf16.h>
#include <cstdint>

#define N_NODES 50000
#define N_EDGES 800000
#define DIM 128

// ---------------- CSR build ----------------

__global__ void count_kernel(const int* __restrict__ rows, int* __restrict__ counts, int ne) {
    int e = blockIdx.x * blockDim.x + threadIdx.x;
    if (e < ne) atomicAdd(&counts[rows[e]], 1);
}

// hierarchical exclusive scan: A (per-block scan), B (scan block sums), C (add)
__global__ void scanA_kernel(const int* __restrict__ counts, int* __restrict__ offs,
                             int* __restrict__ bsum, int n) {
    int t = threadIdx.x;
    int i = blockIdx.x * 1024 + t;
    int v = (i < n) ? counts[i] : 0;
    int x = v;
    // wave-level inclusive scan
    #pragma unroll
    for (int off = 1; off < 64; off <<= 1) {
        int y = __shfl_up(x, off);
        if ((t & 63) >= off) x += y;
    }
    __shared__ int wsum[16];
    if ((t & 63) == 63) wsum[t >> 6] = x;
    __syncthreads();
    if (t < 16) {
        int y = wsum[t];
        #pragma unroll
        for (int off = 1; off < 16; off <<= 1) {
            int z = __shfl_up(y, off);
            if (t >= off) y += z;
        }
        wsum[t] = y;
    }
    __syncthreads();
    int base = (t >> 6) ? wsum[(t >> 6) - 1] : 0;
    int incl = base + x;
    if (i < n) offs[i] = incl - v;     // block-local exclusive
    if (t == 1023) bsum[blockIdx.x] = incl;
}

__global__ void scanB_kernel(int* __restrict__ bsum, int nb) {
    int t = threadIdx.x;  // 64 threads, nb <= 64
    int v = (t < nb) ? bsum[t] : 0;
    int x = v;
    #pragma unroll
    for (int off = 1; off < 64; off <<= 1) {
        int y = __shfl_up(x, off);
        if (t >= off) x += y;
    }
    if (t < nb) bsum[t] = x - v;       // exclusive
}

__global__ void scanC_kernel(int* __restrict__ offs, int* __restrict__ cursor,
                             const int* __restrict__ bsum, int n) {
    int i = blockIdx.x * 1024 + threadIdx.x;
    if (i < n) {
        int o = offs[i] + bsum[blockIdx.x];
        offs[i] = o;
        cursor[i] = o;
    }
}

__global__ void scatter_kernel(const int* __restrict__ rows, const int* __restrict__ cols,
                               const float* __restrict__ vals, int* __restrict__ cursor,
                               int* __restrict__ scol, float* __restrict__ sval, int ne) {
    int e = blockIdx.x * blockDim.x + threadIdx.x;
    if (e < ne) {
        int p = atomicAdd(&cursor[rows[e]], 1);
        scol[p] = cols[e];
        sval[p] = vals[e];
    }
}

// ---------------- tanh(F @ W) f32 GEMM, 32 rows/block, full 128x128 W in LDS ----------------

__global__ __launch_bounds__(256) void gemm_tanh_kernel(const float* __restrict__ F,
                                                        const float* __restrict__ W,
                                                        float* __restrict__ Y, int nrows) {
    __shared__ float Ws[128 * 128];   // 64 KiB, [d][j] row-major
    __shared__ float Fs[32 * 128];    // 16 KiB, [r][d] row-major
    int tid = threadIdx.x;
    int row0 = blockIdx.x * 32;

    for (int i = tid; i < 128 * 128; i += 256) Ws[i] = W[i];
    for (int i = tid; i < 32 * 128; i += 256) {
        int r = i >> 7, d = i & 127;
        int row = row0 + r;
        if (row >= nrows) row = nrows - 1;
        Fs[i] = F[(size_t)row * 128 + d];
    }
    __syncthreads();

    int cg = tid & 31;        // col group: cols cg*4 .. cg*4+3
    int rg = tid >> 5;        // row group: rows rg*4 .. rg*4+3
    float acc[4][4] = {{0.f}};

    #pragma unroll 8
    for (int d = 0; d < 128; ++d) {
        float4 wv = *(const float4*)&Ws[d * 128 + cg * 4];
        float a0 = Fs[(rg * 4 + 0) * 128 + d];
        float a1 = Fs[(rg * 4 + 1) * 128 + d];
        float a2 = Fs[(rg * 4 + 2) * 128 + d];
        float a3 = Fs[(rg * 4 + 3) * 128 + d];
        acc[0][0] += a0 * wv.x; acc[0][1] += a0 * wv.y; acc[0][2] += a0 * wv.z; acc[0][3] += a0 * wv.w;
        acc[1][0] += a1 * wv.x; acc[1][1] += a1 * wv.y; acc[1][2] += a1 * wv.z; acc[1][3] += a1 * wv.w;
        acc[2][0] += a2 * wv.x; acc[2][1] += a2 * wv.y; acc[2][2] += a2 * wv.z; acc[2][3] += a2 * wv.w;
        acc[3][0] += a3 * wv.x; acc[3][1] += a3 * wv.y; acc[3][2] += a3 * wv.z; acc[3][3] += a3 * wv.w;
    }

    #pragma unroll
    for (int i = 0; i < 4; ++i) {
        int row = row0 + rg * 4 + i;
        if (row < nrows) {
            float4 o;
            o.x = tanhf(acc[i][0]); o.y = tanhf(acc[i][1]);
            o.z = tanhf(acc[i][2]); o.w = tanhf(acc[i][3]);
            *(float4*)&Y[(size_t)row * 128 + cg * 4] = o;
        }
    }
}

// ---------------- SpMM: y[r] = sum_e val[e] * x[col[e]], one wave per row ----------------

__global__ __launch_bounds__(256) void spmm_kernel(const int* __restrict__ offs,
                                                   const int* __restrict__ cnts,
                                                   const int* __restrict__ scol,
                                                   const float* __restrict__ sval,
                                                   const float* __restrict__ x,
                                                   float* __restrict__ y, int nrows) {
    int row = blockIdx.x * 4 + (threadIdx.x >> 6);
    if (row >= nrows) return;
    int lane = threadIdx.x & 63;
    int start = offs[row];
    int n = cnts[row];
    const float2* x2 = (const float2*)x;
    float sx = 0.f, sy = 0.f;
    int i = 0;
    for (; i + 4 <= n; i += 4) {
        int   c0 = scol[start + i + 0], c1 = scol[start + i + 1];
        int   c2 = scol[start + i + 2], c3 = scol[start + i + 3];
        float v0 = sval[start + i + 0], v1 = sval[start + i + 1];
        float v2 = sval[start + i + 2], v3 = sval[start + i + 3];
        float2 a0 = x2[(size_t)c0 * 64 + lane];
        float2 a1 = x2[(size_t)c1 * 64 + lane];
        float2 a2 = x2[(size_t)c2 * 64 + lane];
        float2 a3 = x2[(size_t)c3 * 64 + lane];
        sx += v0 * a0.x + v1 * a1.x + v2 * a2.x + v3 * a3.x;
        sy += v0 * a0.y + v1 * a1.y + v2 * a2.y + v3 * a3.y;
    }
    for (; i < n; ++i) {
        int c = scol[start + i];
        float v = sval[start + i];
        float2 a = x2[(size_t)c * 64 + lane];
        sx += v * a.x; sy += v * a.y;
    }
    float2 o; o.x = sx; o.y = sy;
    ((float2*)y)[(size_t)row * 64 + lane] = o;
}

// ---------------- column sums ----------------

__global__ __launch_bounds__(128) void colsum_kernel(const float* __restrict__ f,
                                                     float* __restrict__ out, int nrows) {
    int d = threadIdx.x;  // 128 threads
    float s = 0.f;
    for (int n = blockIdx.x; n < nrows; n += gridDim.x) s += f[(size_t)n * 128 + d];
    atomicAdd(&out[d], s);
}

// ---------------- FC + softmax over order (single block, 128 threads) ----------------

__global__ __launch_bounds__(128) void fc_softmax_kernel(const float* __restrict__ colsum,
                                                         const float* __restrict__ b1,
                                                         const float* __restrict__ b2,
                                                         const float* __restrict__ b3,
                                                         const float* __restrict__ fc1w,
                                                         const float* __restrict__ fc1b,
                                                         const float* __restrict__ fc2w,
                                                         const float* __restrict__ fc2b,
                                                         float* __restrict__ wgt) {
    __shared__ float m[3][128];
    __shared__ float r[3][32];
    int t = threadIdx.x;
    const float inv = 1.0f / (float)N_NODES;
    m[0][t] = colsum[0 * 128 + t] * inv + b1[t];
    m[1][t] = colsum[1 * 128 + t] * inv + b2[t];
    m[2][t] = colsum[2 * 128 + t] * inv + b3[t];
    __syncthreads();
    if (t < 96) {
        int k = t >> 5, j = t & 31;
        float acc = fc1b[j];
        for (int d = 0; d < 128; ++d) acc += m[k][d] * fc1w[d * 32 + j];
        r[k][j] = fmaxf(acc, 0.f);
    }
    __syncthreads();
    float a[3];
    #pragma unroll
    for (int k = 0; k < 3; ++k) {
        float acc = fc2b[t];
        for (int j = 0; j < 32; ++j) acc += r[k][j] * fc2w[j * 128 + t];
        a[k] = acc;
    }
    float mx = fmaxf(a[0], fmaxf(a[1], a[2]));
    float e0 = expf(a[0] - mx), e1 = expf(a[1] - mx), e2 = expf(a[2] - mx);
    float s = e0 + e1 + e2;
    wgt[0 * 128 + t] = e0 / s;
    wgt[1 * 128 + t] = e1 / s;
    wgt[2 * 128 + t] = e2 / s;
}

// ---------------- combine: out = (f1+b1)*w0 + (f2+b2)*w1 + (f3+b3)*w2 (in place on f1) ----

__global__ __launch_bounds__(256) void combine_kernel(float* __restrict__ out,
                                                      const float* __restrict__ f2,
                                                      const float* __restrict__ f3,
                                                      const float* __restrict__ b1,
                                                      const float* __restrict__ b2,
                                                      const float* __restrict__ b3,
                                                      const float* __restrict__ wgt) {
    const int total = N_NODES * 32;  // float4 count
    int idx0 = blockIdx.x * blockDim.x + threadIdx.x;
    int stride = gridDim.x * blockDim.x;  // multiple of 32 -> q constant per thread
    int qb = idx0 & 31;
    const float4* wgt4 = (const float4*)wgt;
    float4 W0 = wgt4[qb], W1 = wgt4[32 + qb], W2 = wgt4[64 + qb];
    float4 B1 = ((const float4*)b1)[qb];
    float4 B2 = ((const float4*)b2)[qb];
    float4 B3 = ((const float4*)b3)[qb];
    for (int idx = idx0; idx < total; idx += stride) {
        float4 v1 = ((const float4*)out)[idx];
        float4 v2 = ((const float4*)f2)[idx];
        float4 v3 = ((const float4*)f3)[idx];
        float4 o;
        o.x = (v1.x + B1.x) * W0.x + (v2.x + B2.x) * W1.x + (v3.x + B3.x) * W2.x;
        o.y = (v1.y + B1.y) * W0.y + (v2.y + B2.y) * W1.y + (v3.y + B3.y) * W2.y;
        o.z = (v1.z + B1.z) * W0.z + (v2.z + B2.z) * W1.z + (v3.z + B3.z) * W2.z;
        o.w = (v1.w + B1.w) * W0.w + (v2.w + B2.w) * W1.w + (v3.w + B3.w) * W2.w;
        ((float4*)out)[idx] = o;
    }
}

// ---------------- launch ----------------

extern "C" void kernel_launch(void* const* d_in, const int* in_sizes, int n_in,
                              void* d_out, int out_size, void* d_ws, size_t ws_size,
                              hipStream_t stream) {
    const float* F    = (const float*)d_in[0];
    const int*   erow = (const int*)d_in[1];
    const int*   ecol = (const int*)d_in[2];
    const float* eval_ = (const float*)d_in[3];
    const float* w1 = (const float*)d_in[4];  const float* b1 = (const float*)d_in[5];
    const float* w2 = (const float*)d_in[6];  const float* b2 = (const float*)d_in[7];
    const float* w3 = (const float*)d_in[8];  const float* b3 = (const float*)d_in[9];
    const float* fc1w = (const float*)d_in[10]; const float* fc1b = (const float*)d_in[11];
    const float* fc2w = (const float*)d_in[12]; const float* fc2b = (const float*)d_in[13];
    float* out = (float*)d_out;

    char* ws = (char*)d_ws;
    size_t off = 0;
    auto alloc = [&](size_t bytes) -> void* {
        off = (off + 255) & ~(size_t)255;
        void* p = ws + off;
        off += bytes;
        return p;
    };
    const size_t matBytes = (size_t)N_NODES * DIM * sizeof(float);  // 25.6 MB
    float* t0 = (float*)alloc(matBytes);
    float* t1 = (float*)alloc(matBytes);
    float* t2 = (float*)alloc(matBytes);
    int*   scol   = (int*)alloc((size_t)N_EDGES * sizeof(int));
    float* sval   = (float*)alloc((size_t)N_EDGES * sizeof(float));
    int*   counts = (int*)alloc((size_t)N_NODES * sizeof(int));
    int*   offs   = (int*)alloc((size_t)N_NODES * sizeof(int));
    int*   cursor = (int*)alloc((size_t)N_NODES * sizeof(int));
    int*   bsum   = (int*)alloc(64 * sizeof(int));
    float* colsum = (float*)alloc(3 * 128 * sizeof(float));
    float* wgt    = (float*)alloc(3 * 128 * sizeof(float));

    const int nScanBlocks = (N_NODES + 1023) / 1024;  // 49

    // --- CSR build ---
    hipMemsetAsync(counts, 0, (size_t)N_NODES * sizeof(int), stream);
    count_kernel<<<(N_EDGES + 255) / 256, 256, 0, stream>>>(erow, counts, N_EDGES);
    scanA_kernel<<<nScanBlocks, 1024, 0, stream>>>(counts, offs, bsum, N_NODES);
    scanB_kernel<<<1, 64, 0, stream>>>(bsum, nScanBlocks);
    scanC_kernel<<<nScanBlocks, 1024, 0, stream>>>(offs, cursor, bsum, N_NODES);
    scatter_kernel<<<(N_EDGES + 255) / 256, 256, 0, stream>>>(erow, ecol, eval_, cursor,
                                                              scol, sval, N_EDGES);

    const int gemmGrid = (N_NODES + 31) / 32;   // 1563
    const int spmmGrid = (N_NODES + 3) / 4;     // 12500

    // --- branch 3: f3 = A^3 tanh(F w3)  -> ends in t1 ---
    gemm_tanh_kernel<<<gemmGrid, 256, 0, stream>>>(F, w3, t0, N_NODES);
    spmm_kernel<<<spmmGrid, 256, 0, stream>>>(offs, counts, scol, sval, t0, t1, N_NODES);
    spmm_kernel<<<spmmGrid, 256, 0, stream>>>(offs, counts, scol, sval, t1, t0, N_NODES);
    spmm_kernel<<<spmmGrid, 256, 0, stream>>>(offs, counts, scol, sval, t0, t1, N_NODES);
    // --- branch 2: f2 = A^2 tanh(F w2)  -> ends in t0 ---
    gemm_tanh_kernel<<<gemmGrid, 256, 0, stream>>>(F, w2, t0, N_NODES);
    spmm_kernel<<<spmmGrid, 256, 0, stream>>>(offs, counts, scol, sval, t0, t2, N_NODES);
    spmm_kernel<<<spmmGrid, 256, 0, stream>>>(offs, counts, scol, sval, t2, t0, N_NODES);
    // --- branch 1: f1 = A tanh(F w1)    -> ends in d_out ---
    gemm_tanh_kernel<<<gemmGrid, 256, 0, stream>>>(F, w1, t2, N_NODES);
    spmm_kernel<<<spmmGrid, 256, 0, stream>>>(offs, counts, scol, sval, t2, out, N_NODES);

    // --- column sums: f1=out (k=0), f2=t0 (k=1), f3=t1 (k=2) ---
    hipMemsetAsync(colsum, 0, 3 * 128 * sizeof(float), stream);
    colsum_kernel<<<512, 128, 0, stream>>>(out, colsum + 0 * 128, N_NODES);
    colsum_kernel<<<512, 128, 0, stream>>>(t0,  colsum + 1 * 128, N_NODES);
    colsum_kernel<<<512, 128, 0, stream>>>(t1,  colsum + 2 * 128, N_NODES);

    // --- FC + softmax -> per-dim order weights ---
    fc_softmax_kernel<<<1, 128, 0, stream>>>(colsum, b1, b2, b3, fc1w, fc1b, fc2w, fc2b, wgt);

    // --- weighted combine (in place on d_out) ---
    combine_kernel<<<2048, 256, 0, stream>>>(out, t0, t1, b1, b2, b3, wgt);
}

// Round 2
// 459.755 us; speedup vs baseline: 1.4859x; 1.4859x over previous
//
#include <hip/hip_runtime.h>
#include <hip/hip_bf16.h>
#include <cstdint>

#define N_NODES 50000
#define N_EDGES 800000
#define DIM 128

// ---------------- bf16 helpers (manual, RNE) ----------------

__device__ inline unsigned pack_bf16x2(float lo, float hi) {
    unsigned a = __float_as_uint(lo), b = __float_as_uint(hi);
    a = (a + 0x7FFFu + ((a >> 16) & 1u)) >> 16;
    b = (b + 0x7FFFu + ((b >> 16) & 1u)) & 0xFFFF0000u;
    return a | b;
}
__device__ inline float bf_lo(unsigned u) { return __uint_as_float(u << 16); }
__device__ inline float bf_hi(unsigned u) { return __uint_as_float(u & 0xFFFF0000u); }

// ---------------- CSR build ----------------

__global__ void count_kernel(const int* __restrict__ rows, int* __restrict__ counts, int ne) {
    int e = blockIdx.x * blockDim.x + threadIdx.x;
    if (e < ne) atomicAdd(&counts[rows[e]], 1);
}

__global__ void scanA_kernel(const int* __restrict__ counts, int* __restrict__ offs,
                             int* __restrict__ bsum, int n) {
    int t = threadIdx.x;
    int i = blockIdx.x * 1024 + t;
    int v = (i < n) ? counts[i] : 0;
    int x = v;
    #pragma unroll
    for (int off = 1; off < 64; off <<= 1) {
        int y = __shfl_up(x, off);
        if ((t & 63) >= off) x += y;
    }
    __shared__ int wsum[16];
    if ((t & 63) == 63) wsum[t >> 6] = x;
    __syncthreads();
    if (t < 16) {
        int y = wsum[t];
        #pragma unroll
        for (int off = 1; off < 16; off <<= 1) {
            int z = __shfl_up(y, off);
            if (t >= off) y += z;
        }
        wsum[t] = y;
    }
    __syncthreads();
    int base = (t >> 6) ? wsum[(t >> 6) - 1] : 0;
    int incl = base + x;
    if (i < n) offs[i] = incl - v;
    if (t == 1023) bsum[blockIdx.x] = incl;
}

__global__ void scanB_kernel(int* __restrict__ bsum, int nb) {
    int t = threadIdx.x;
    int v = (t < nb) ? bsum[t] : 0;
    int x = v;
    #pragma unroll
    for (int off = 1; off < 64; off <<= 1) {
        int y = __shfl_up(x, off);
        if (t >= off) x += y;
    }
    if (t < nb) bsum[t] = x - v;
}

__global__ void scanC_kernel(int* __restrict__ offs, int* __restrict__ cursor,
                             const int* __restrict__ bsum, int n) {
    int i = blockIdx.x * 1024 + threadIdx.x;
    if (i < n) {
        int o = offs[i] + bsum[blockIdx.x];
        offs[i] = o;
        cursor[i] = o;
    }
}

// packed scatter: one 8B store per edge
__global__ void scatter_kernel(const int* __restrict__ rows, const int* __restrict__ cols,
                               const float* __restrict__ vals, int* __restrict__ cursor,
                               int2* __restrict__ ep, int ne) {
    int e = blockIdx.x * blockDim.x + threadIdx.x;
    if (e < ne) {
        int p = atomicAdd(&cursor[rows[e]], 1);
        ep[p] = make_int2(cols[e], __float_as_int(vals[e]));
    }
}

// ---------------- tanh(F @ W) f32 GEMM -> packed bf16x2 output ----------------

__global__ __launch_bounds__(256) void gemm_tanh_kernel(const float* __restrict__ F,
                                                        const float* __restrict__ W,
                                                        unsigned* __restrict__ Y, int nrows) {
    __shared__ float Ws[128 * 128];   // [d][j]
    __shared__ float Fs[32 * 128];    // [r][d]
    int tid = threadIdx.x;
    int row0 = blockIdx.x * 32;

    for (int i = tid; i < 128 * 128; i += 256) Ws[i] = W[i];
    for (int i = tid; i < 32 * 128; i += 256) {
        int r = i >> 7, d = i & 127;
        int row = row0 + r;
        if (row >= nrows) row = nrows - 1;
        Fs[i] = F[(size_t)row * 128 + d];
    }
    __syncthreads();

    int cg = tid & 31;        // cols cg*4 .. cg*4+3
    int rg = tid >> 5;        // rows rg*4 .. rg*4+3
    float acc[4][4] = {{0.f}};

    #pragma unroll 8
    for (int d = 0; d < 128; ++d) {
        float4 wv = *(const float4*)&Ws[d * 128 + cg * 4];
        float a0 = Fs[(rg * 4 + 0) * 128 + d];
        float a1 = Fs[(rg * 4 + 1) * 128 + d];
        float a2 = Fs[(rg * 4 + 2) * 128 + d];
        float a3 = Fs[(rg * 4 + 3) * 128 + d];
        acc[0][0] += a0 * wv.x; acc[0][1] += a0 * wv.y; acc[0][2] += a0 * wv.z; acc[0][3] += a0 * wv.w;
        acc[1][0] += a1 * wv.x; acc[1][1] += a1 * wv.y; acc[1][2] += a1 * wv.z; acc[1][3] += a1 * wv.w;
        acc[2][0] += a2 * wv.x; acc[2][1] += a2 * wv.y; acc[2][2] += a2 * wv.z; acc[2][3] += a2 * wv.w;
        acc[3][0] += a3 * wv.x; acc[3][1] += a3 * wv.y; acc[3][2] += a3 * wv.z; acc[3][3] += a3 * wv.w;
    }

    #pragma unroll
    for (int i = 0; i < 4; ++i) {
        int row = row0 + rg * 4 + i;
        if (row < nrows) {
            uint2 o;
            o.x = pack_bf16x2(tanhf(acc[i][0]), tanhf(acc[i][1]));
            o.y = pack_bf16x2(tanhf(acc[i][2]), tanhf(acc[i][3]));
            *(uint2*)&Y[(size_t)row * 64 + cg * 2] = o;
        }
    }
}

// ---------------- SpMM: bf16x2 gather, f32 accumulate, bf16 or f32 out ----------------
// one wave per row; lane handles dims {2*lane, 2*lane+1}

template <bool F32OUT>
__global__ __launch_bounds__(256) void spmm_kernel(const int* __restrict__ offs,
                                                   const int* __restrict__ cnts,
                                                   const int2* __restrict__ ep,
                                                   const unsigned* __restrict__ x,
                                                   void* __restrict__ yv, int nrows) {
    int row = blockIdx.x * 4 + (threadIdx.x >> 6);
    if (row >= nrows) return;
    int lane = threadIdx.x & 63;
    int start = __builtin_amdgcn_readfirstlane(offs[row]);
    int n     = __builtin_amdgcn_readfirstlane(cnts[row]);
    float sx = 0.f, sy = 0.f;
    int i = 0;
    for (; i + 8 <= n; i += 8) {
        int2 p0 = ep[start + i + 0], p1 = ep[start + i + 1];
        int2 p2 = ep[start + i + 2], p3 = ep[start + i + 3];
        int2 p4 = ep[start + i + 4], p5 = ep[start + i + 5];
        int2 p6 = ep[start + i + 6], p7 = ep[start + i + 7];
        unsigned a0 = x[(size_t)p0.x * 64 + lane];
        unsigned a1 = x[(size_t)p1.x * 64 + lane];
        unsigned a2 = x[(size_t)p2.x * 64 + lane];
        unsigned a3 = x[(size_t)p3.x * 64 + lane];
        unsigned a4 = x[(size_t)p4.x * 64 + lane];
        unsigned a5 = x[(size_t)p5.x * 64 + lane];
        unsigned a6 = x[(size_t)p6.x * 64 + lane];
        unsigned a7 = x[(size_t)p7.x * 64 + lane];
        float v0 = __int_as_float(p0.y), v1 = __int_as_float(p1.y);
        float v2 = __int_as_float(p2.y), v3 = __int_as_float(p3.y);
        float v4 = __int_as_float(p4.y), v5 = __int_as_float(p5.y);
        float v6 = __int_as_float(p6.y), v7 = __int_as_float(p7.y);
        sx += v0 * bf_lo(a0) + v1 * bf_lo(a1) + v2 * bf_lo(a2) + v3 * bf_lo(a3)
            + v4 * bf_lo(a4) + v5 * bf_lo(a5) + v6 * bf_lo(a6) + v7 * bf_lo(a7);
        sy += v0 * bf_hi(a0) + v1 * bf_hi(a1) + v2 * bf_hi(a2) + v3 * bf_hi(a3)
            + v4 * bf_hi(a4) + v5 * bf_hi(a5) + v6 * bf_hi(a6) + v7 * bf_hi(a7);
    }
    for (; i < n; ++i) {
        int2 p = ep[start + i];
        unsigned a = x[(size_t)p.x * 64 + lane];
        float v = __int_as_float(p.y);
        sx += v * bf_lo(a);
        sy += v * bf_hi(a);
    }
    if (F32OUT) {
        float2 o; o.x = sx; o.y = sy;
        ((float2*)yv)[(size_t)row * 64 + lane] = o;
    } else {
        ((unsigned*)yv)[(size_t)row * 64 + lane] = pack_bf16x2(sx, sy);
    }
}

// ---------------- column sums (3 matrices in one launch) ----------------

__global__ __launch_bounds__(128) void colsum_kernel(const float* __restrict__ f1,
                                                     const float* __restrict__ f2,
                                                     const float* __restrict__ f3,
                                                     float* __restrict__ out, int nrows) {
    const float* f = (blockIdx.y == 0) ? f1 : (blockIdx.y == 1) ? f2 : f3;
    int d = threadIdx.x;
    float s = 0.f;
    for (int n = blockIdx.x; n < nrows; n += gridDim.x) s += f[(size_t)n * 128 + d];
    atomicAdd(&out[blockIdx.y * 128 + d], s);
}

// ---------------- FC + softmax over order ----------------

__global__ __launch_bounds__(128) void fc_softmax_kernel(const float* __restrict__ colsum,
                                                         const float* __restrict__ b1,
                                                         const float* __restrict__ b2,
                                                         const float* __restrict__ b3,
                                                         const float* __restrict__ fc1w,
                                                         const float* __restrict__ fc1b,
                                                         const float* __restrict__ fc2w,
                                                         const float* __restrict__ fc2b,
                                                         float* __restrict__ wgt) {
    __shared__ float m[3][128];
    __shared__ float r[3][32];
    int t = threadIdx.x;
    const float inv = 1.0f / (float)N_NODES;
    m[0][t] = colsum[0 * 128 + t] * inv + b1[t];
    m[1][t] = colsum[1 * 128 + t] * inv + b2[t];
    m[2][t] = colsum[2 * 128 + t] * inv + b3[t];
    __syncthreads();
    if (t < 96) {
        int k = t >> 5, j = t & 31;
        float acc = fc1b[j];
        for (int d = 0; d < 128; ++d) acc += m[k][d] * fc1w[d * 32 + j];
        r[k][j] = fmaxf(acc, 0.f);
    }
    __syncthreads();
    float a[3];
    #pragma unroll
    for (int k = 0; k < 3; ++k) {
        float acc = fc2b[t];
        for (int j = 0; j < 32; ++j) acc += r[k][j] * fc2w[j * 128 + t];
        a[k] = acc;
    }
    float mx = fmaxf(a[0], fmaxf(a[1], a[2]));
    float e0 = expf(a[0] - mx), e1 = expf(a[1] - mx), e2 = expf(a[2] - mx);
    float s = e0 + e1 + e2;
    wgt[0 * 128 + t] = e0 / s;
    wgt[1 * 128 + t] = e1 / s;
    wgt[2 * 128 + t] = e2 / s;
}

// ---------------- combine: out = (f1+b1)*w0 + (f2+b2)*w1 + (f3+b3)*w2 ----------------

__global__ __launch_bounds__(256) void combine_kernel(float* __restrict__ out,
                                                      const float* __restrict__ f2,
                                                      const float* __restrict__ f3,
                                                      const float* __restrict__ b1,
                                                      const float* __restrict__ b2,
                                                      const float* __restrict__ b3,
                                                      const float* __restrict__ wgt) {
    const int total = N_NODES * 32;  // float4 count
    int idx0 = blockIdx.x * blockDim.x + threadIdx.x;
    int stride = gridDim.x * blockDim.x;
    int qb = idx0 & 31;
    const float4* wgt4 = (const float4*)wgt;
    float4 W0 = wgt4[qb], W1 = wgt4[32 + qb], W2 = wgt4[64 + qb];
    float4 B1 = ((const float4*)b1)[qb];
    float4 B2 = ((const float4*)b2)[qb];
    float4 B3 = ((const float4*)b3)[qb];
    for (int idx = idx0; idx < total; idx += stride) {
        float4 v1 = ((const float4*)out)[idx];
        float4 v2 = ((const float4*)f2)[idx];
        float4 v3 = ((const float4*)f3)[idx];
        float4 o;
        o.x = (v1.x + B1.x) * W0.x + (v2.x + B2.x) * W1.x + (v3.x + B3.x) * W2.x;
        o.y = (v1.y + B1.y) * W0.y + (v2.y + B2.y) * W1.y + (v3.y + B3.y) * W2.y;
        o.z = (v1.z + B1.z) * W0.z + (v2.z + B2.z) * W1.z + (v3.z + B3.z) * W2.z;
        o.w = (v1.w + B1.w) * W0.w + (v2.w + B2.w) * W1.w + (v3.w + B3.w) * W2.w;
        ((float4*)out)[idx] = o;
    }
}

// ---------------- launch ----------------

extern "C" void kernel_launch(void* const* d_in, const int* in_sizes, int n_in,
                              void* d_out, int out_size, void* d_ws, size_t ws_size,
                              hipStream_t stream) {
    const float* F    = (const float*)d_in[0];
    const int*   erow = (const int*)d_in[1];
    const int*   ecol = (const int*)d_in[2];
    const float* eval_ = (const float*)d_in[3];
    const float* w1 = (const float*)d_in[4];  const float* b1 = (const float*)d_in[5];
    const float* w2 = (const float*)d_in[6];  const float* b2 = (const float*)d_in[7];
    const float* w3 = (const float*)d_in[8];  const float* b3 = (const float*)d_in[9];
    const float* fc1w = (const float*)d_in[10]; const float* fc1b = (const float*)d_in[11];
    const float* fc2w = (const float*)d_in[12]; const float* fc2b = (const float*)d_in[13];
    float* out = (float*)d_out;

    char* ws = (char*)d_ws;
    size_t off = 0;
    auto alloc = [&](size_t bytes) -> void* {
        off = (off + 255) & ~(size_t)255;
        void* p = ws + off;
        off += bytes;
        return p;
    };
    const size_t bfBytes = (size_t)N_NODES * 64 * sizeof(unsigned);  // 12.8 MB
    const size_t f32Bytes = (size_t)N_NODES * DIM * sizeof(float);   // 25.6 MB
    unsigned* a0 = (unsigned*)alloc(bfBytes);
    unsigned* a1 = (unsigned*)alloc(bfBytes);
    float* t0f = (float*)alloc(f32Bytes);   // f2
    float* t1f = (float*)alloc(f32Bytes);   // f3
    int2*  ep     = (int2*)alloc((size_t)N_EDGES * sizeof(int2));
    int*   counts = (int*)alloc((size_t)N_NODES * sizeof(int));
    int*   offs   = (int*)alloc((size_t)N_NODES * sizeof(int));
    int*   cursor = (int*)alloc((size_t)N_NODES * sizeof(int));
    int*   bsum   = (int*)alloc(64 * sizeof(int));
    float* colsum = (float*)alloc(3 * 128 * sizeof(float));
    float* wgt    = (float*)alloc(3 * 128 * sizeof(float));

    const int nScanBlocks = (N_NODES + 1023) / 1024;  // 49

    // --- CSR build ---
    hipMemsetAsync(counts, 0, (size_t)N_NODES * sizeof(int), stream);
    count_kernel<<<(N_EDGES + 255) / 256, 256, 0, stream>>>(erow, counts, N_EDGES);
    scanA_kernel<<<nScanBlocks, 1024, 0, stream>>>(counts, offs, bsum, N_NODES);
    scanB_kernel<<<1, 64, 0, stream>>>(bsum, nScanBlocks);
    scanC_kernel<<<nScanBlocks, 1024, 0, stream>>>(offs, cursor, bsum, N_NODES);
    scatter_kernel<<<(N_EDGES + 255) / 256, 256, 0, stream>>>(erow, ecol, eval_, cursor, ep, N_EDGES);

    const int gemmGrid = (N_NODES + 31) / 32;   // 1563
    const int spmmGrid = (N_NODES + 3) / 4;     // 12500

    // --- branch 3: f3 = A^3 tanh(F w3) -> t1f ---
    gemm_tanh_kernel<<<gemmGrid, 256, 0, stream>>>(F, w3, a0, N_NODES);
    spmm_kernel<false><<<spmmGrid, 256, 0, stream>>>(offs, counts, ep, a0, a1, N_NODES);
    spmm_kernel<false><<<spmmGrid, 256, 0, stream>>>(offs, counts, ep, a1, a0, N_NODES);
    spmm_kernel<true ><<<spmmGrid, 256, 0, stream>>>(offs, counts, ep, a0, t1f, N_NODES);
    // --- branch 2: f2 = A^2 tanh(F w2) -> t0f ---
    gemm_tanh_kernel<<<gemmGrid, 256, 0, stream>>>(F, w2, a1, N_NODES);
    spmm_kernel<false><<<spmmGrid, 256, 0, stream>>>(offs, counts, ep, a1, a0, N_NODES);
    spmm_kernel<true ><<<spmmGrid, 256, 0, stream>>>(offs, counts, ep, a0, t0f, N_NODES);
    // --- branch 1: f1 = A tanh(F w1) -> d_out ---
    gemm_tanh_kernel<<<gemmGrid, 256, 0, stream>>>(F, w1, a1, N_NODES);
    spmm_kernel<true ><<<spmmGrid, 256, 0, stream>>>(offs, counts, ep, a1, out, N_NODES);

    // --- column sums: k=0 -> f1=out, k=1 -> f2=t0f, k=2 -> f3=t1f ---
    hipMemsetAsync(colsum, 0, 3 * 128 * sizeof(float), stream);
    colsum_kernel<<<dim3(512, 3), 128, 0, stream>>>(out, t0f, t1f, colsum, N_NODES);

    // --- FC + softmax ---
    fc_softmax_kernel<<<1, 128, 0, stream>>>(colsum, b1, b2, b3, fc1w, fc1b, fc2w, fc2b, wgt);

    // --- weighted combine (in place on d_out) ---
    combine_kernel<<<2048, 256, 0, stream>>>(out, t0f, t1f, b1, b2, b3, wgt);
}

// Round 3
// 437.090 us; speedup vs baseline: 1.5629x; 1.0519x over previous
//
#include <hip/hip_runtime.h>
#include <hip/hip_bf16.h>
#include <cstdint>

#define N_NODES 50000
#define N_EDGES 800000
#define DIM 128

// ---------------- bf16 helpers (manual, RNE) ----------------

__device__ inline unsigned pack_bf16x2(float lo, float hi) {
    unsigned a = __float_as_uint(lo), b = __float_as_uint(hi);
    a = (a + 0x7FFFu + ((a >> 16) & 1u)) >> 16;
    b = (b + 0x7FFFu + ((b >> 16) & 1u)) & 0xFFFF0000u;
    return a | b;
}
__device__ inline float bf_lo(unsigned u) { return __uint_as_float(u << 16); }
__device__ inline float bf_hi(unsigned u) { return __uint_as_float(u & 0xFFFF0000u); }

// ---------------- CSR build ----------------

__global__ void count_kernel(const int* __restrict__ rows, int* __restrict__ counts, int ne) {
    int e = blockIdx.x * blockDim.x + threadIdx.x;
    if (e < ne) atomicAdd(&counts[rows[e]], 1);
}

__global__ void scanA_kernel(const int* __restrict__ counts, int* __restrict__ offs,
                             int* __restrict__ bsum, int n) {
    int t = threadIdx.x;
    int i = blockIdx.x * 1024 + t;
    int v = (i < n) ? counts[i] : 0;
    int x = v;
    #pragma unroll
    for (int off = 1; off < 64; off <<= 1) {
        int y = __shfl_up(x, off);
        if ((t & 63) >= off) x += y;
    }
    __shared__ int wsum[16];
    if ((t & 63) == 63) wsum[t >> 6] = x;
    __syncthreads();
    if (t < 16) {
        int y = wsum[t];
        #pragma unroll
        for (int off = 1; off < 16; off <<= 1) {
            int z = __shfl_up(y, off);
            if (t >= off) y += z;
        }
        wsum[t] = y;
    }
    __syncthreads();
    int base = (t >> 6) ? wsum[(t >> 6) - 1] : 0;
    int incl = base + x;
    if (i < n) offs[i] = incl - v;
    if (t == 1023) bsum[blockIdx.x] = incl;
}

__global__ void scanB_kernel(int* __restrict__ bsum, int nb) {
    int t = threadIdx.x;
    int v = (t < nb) ? bsum[t] : 0;
    int x = v;
    #pragma unroll
    for (int off = 1; off < 64; off <<= 1) {
        int y = __shfl_up(x, off);
        if (t >= off) x += y;
    }
    if (t < nb) bsum[t] = x - v;
}

__global__ void scanC_kernel(int* __restrict__ offs, int* __restrict__ cursor,
                             const int* __restrict__ bsum, int n) {
    int i = blockIdx.x * 1024 + threadIdx.x;
    if (i < n) {
        int o = offs[i] + bsum[blockIdx.x];
        offs[i] = o;
        cursor[i] = o;
    }
}

// packed scatter: one 4B store per edge (u16 col | bf16 val in high bits)
__global__ void scatter_kernel(const int* __restrict__ rows, const int* __restrict__ cols,
                               const float* __restrict__ vals, int* __restrict__ cursor,
                               unsigned* __restrict__ ep, int ne) {
    int e = blockIdx.x * blockDim.x + threadIdx.x;
    if (e < ne) {
        int p = atomicAdd(&cursor[rows[e]], 1);
        unsigned bb = __float_as_uint(vals[e]);
        unsigned pb = (bb + 0x7FFFu + ((bb >> 16) & 1u)) & 0xFFFF0000u;
        ep[p] = pb | (unsigned)cols[e];
    }
}

// ---------------- fused 3-branch tanh(F @ Wb) GEMM -> interleaved bf16 table ----------------
// T1 row layout (dwords, 192/row): [h3 (64) | h2 (64) | h1 (64)], each dword = bf16x2 dims

__global__ __launch_bounds__(256) void gemm_tanh3_kernel(const float* __restrict__ F,
                                                         const float* __restrict__ w3,
                                                         const float* __restrict__ w2,
                                                         const float* __restrict__ w1,
                                                         unsigned* __restrict__ T1, int nrows) {
    __shared__ float Ws[128 * 128];   // [d][j]
    __shared__ float Fs[32 * 128];    // [r][d]
    int tid = threadIdx.x;
    int row0 = blockIdx.x * 32;

    for (int i = tid; i < 32 * 128; i += 256) {
        int r = i >> 7, d = i & 127;
        int row = row0 + r;
        if (row >= nrows) row = nrows - 1;
        Fs[i] = F[(size_t)row * 128 + d];
    }

    int cg = tid & 31;        // cols cg*4 .. cg*4+3
    int rg = tid >> 5;        // rows rg*4 .. rg*4+3

    for (int b = 0; b < 3; ++b) {
        const float* W = (b == 0) ? w3 : (b == 1) ? w2 : w1;
        __syncthreads();      // Fs ready / previous branch's compute done reading Ws
        for (int i = tid; i < 128 * 128; i += 256) Ws[i] = W[i];
        __syncthreads();

        float acc[4][4] = {{0.f}};
        #pragma unroll 8
        for (int d = 0; d < 128; ++d) {
            float4 wv = *(const float4*)&Ws[d * 128 + cg * 4];
            float a0 = Fs[(rg * 4 + 0) * 128 + d];
            float a1 = Fs[(rg * 4 + 1) * 128 + d];
            float a2 = Fs[(rg * 4 + 2) * 128 + d];
            float a3 = Fs[(rg * 4 + 3) * 128 + d];
            acc[0][0] += a0 * wv.x; acc[0][1] += a0 * wv.y; acc[0][2] += a0 * wv.z; acc[0][3] += a0 * wv.w;
            acc[1][0] += a1 * wv.x; acc[1][1] += a1 * wv.y; acc[1][2] += a1 * wv.z; acc[1][3] += a1 * wv.w;
            acc[2][0] += a2 * wv.x; acc[2][1] += a2 * wv.y; acc[2][2] += a2 * wv.z; acc[2][3] += a2 * wv.w;
            acc[3][0] += a3 * wv.x; acc[3][1] += a3 * wv.y; acc[3][2] += a3 * wv.z; acc[3][3] += a3 * wv.w;
        }

        #pragma unroll
        for (int i = 0; i < 4; ++i) {
            int row = row0 + rg * 4 + i;
            if (row < nrows) {
                uint2 o;
                o.x = pack_bf16x2(tanhf(acc[i][0]), tanhf(acc[i][1]));
                o.y = pack_bf16x2(tanhf(acc[i][2]), tanhf(acc[i][3]));
                *(uint2*)&T1[(size_t)row * 192 + b * 64 + cg * 2] = o;
            }
        }
    }
}

// ---------------- batched SpMM stage ----------------
// x: NCHUNK*64 dwords per row (bf16x2). Chunks 0..NCHUNK-2 -> ob0 (stride (NCHUNK-1)*64).
// Final chunk -> f32 (fout) if F32FINAL else bf16 (obf). Final chunk also column-summed
// into csum (8-way replicated by blockIdx&7).
// 8 rows per block (512 threads); grid = 6250 exactly covers 50000 rows.

template <int NCHUNK, bool F32FINAL>
__global__ __launch_bounds__(512) void spmm_stage_kernel(const int* __restrict__ offs,
                                                         const int* __restrict__ cnts,
                                                         const unsigned* __restrict__ ep,
                                                         const unsigned* __restrict__ x,
                                                         unsigned* __restrict__ ob0,
                                                         unsigned* __restrict__ obf,
                                                         float2* __restrict__ fout,
                                                         float* __restrict__ csum) {
    __shared__ float cs[128];
    int tid = threadIdx.x;
    if (tid < 128) cs[tid] = 0.f;
    __syncthreads();

    int row = blockIdx.x * 8 + (tid >> 6);
    int lane = tid & 63;
    int start = __builtin_amdgcn_readfirstlane(offs[row]);
    int n     = __builtin_amdgcn_readfirstlane(cnts[row]);

    float ax[NCHUNK], ay[NCHUNK];
    #pragma unroll
    for (int c = 0; c < NCHUNK; ++c) { ax[c] = 0.f; ay[c] = 0.f; }

    const unsigned* xl = x + lane;
    constexpr int U = (NCHUNK == 1) ? 8 : 4;
    int i = 0;
    for (; i + U <= n; i += U) {
        unsigned p[U];
        #pragma unroll
        for (int u = 0; u < U; ++u) p[u] = ep[start + i + u];
        unsigned g[U][NCHUNK];
        #pragma unroll
        for (int u = 0; u < U; ++u) {
            unsigned b = (p[u] & 0xFFFFu) * (unsigned)(NCHUNK * 64);
            #pragma unroll
            for (int c = 0; c < NCHUNK; ++c) g[u][c] = xl[b + c * 64];
        }
        #pragma unroll
        for (int u = 0; u < U; ++u) {
            float v = __uint_as_float(p[u] & 0xFFFF0000u);
            #pragma unroll
            for (int c = 0; c < NCHUNK; ++c) {
                ax[c] += v * bf_lo(g[u][c]);
                ay[c] += v * bf_hi(g[u][c]);
            }
        }
    }
    for (; i < n; ++i) {
        unsigned p = ep[start + i];
        unsigned b = (p & 0xFFFFu) * (unsigned)(NCHUNK * 64);
        float v = __uint_as_float(p & 0xFFFF0000u);
        #pragma unroll
        for (int c = 0; c < NCHUNK; ++c) {
            unsigned gg = xl[b + c * 64];
            ax[c] += v * bf_lo(gg);
            ay[c] += v * bf_hi(gg);
        }
    }

    // non-final chunks -> ob0 (bf16)
    #pragma unroll
    for (int c = 0; c < NCHUNK - 1; ++c)
        ob0[(size_t)row * ((NCHUNK - 1) * 64) + c * 64 + lane] = pack_bf16x2(ax[c], ay[c]);

    // final chunk
    float fx = ax[NCHUNK - 1], fy = ay[NCHUNK - 1];
    if (F32FINAL) {
        float2 o; o.x = fx; o.y = fy;
        fout[(size_t)row * 64 + lane] = o;
    } else {
        obf[(size_t)row * 64 + lane] = pack_bf16x2(fx, fy);
    }
    atomicAdd(&cs[2 * lane + 0], fx);
    atomicAdd(&cs[2 * lane + 1], fy);
    __syncthreads();
    if (tid < 128) atomicAdd(&csum[(blockIdx.x & 7) * 384 + tid], cs[tid]);
}

// ---------------- FC + softmax over order ----------------

__global__ __launch_bounds__(128) void fc_softmax_kernel(const float* __restrict__ csum,
                                                         const float* __restrict__ b1,
                                                         const float* __restrict__ b2,
                                                         const float* __restrict__ b3,
                                                         const float* __restrict__ fc1w,
                                                         const float* __restrict__ fc1b,
                                                         const float* __restrict__ fc2w,
                                                         const float* __restrict__ fc2b,
                                                         float* __restrict__ wgt) {
    __shared__ float m[3][128];
    __shared__ float r[3][32];
    int t = threadIdx.x;
    const float inv = 1.0f / (float)N_NODES;
    #pragma unroll
    for (int k = 0; k < 3; ++k) {
        float s = 0.f;
        #pragma unroll
        for (int rep = 0; rep < 8; ++rep) s += csum[rep * 384 + k * 128 + t];
        const float* bk = (k == 0) ? b1 : (k == 1) ? b2 : b3;
        m[k][t] = s * inv + bk[t];
    }
    __syncthreads();
    if (t < 96) {
        int k = t >> 5, j = t & 31;
        float acc = fc1b[j];
        for (int d = 0; d < 128; ++d) acc += m[k][d] * fc1w[d * 32 + j];
        r[k][j] = fmaxf(acc, 0.f);
    }
    __syncthreads();
    float a[3];
    #pragma unroll
    for (int k = 0; k < 3; ++k) {
        float acc = fc2b[t];
        for (int j = 0; j < 32; ++j) acc += r[k][j] * fc2w[j * 128 + t];
        a[k] = acc;
    }
    float mx = fmaxf(a[0], fmaxf(a[1], a[2]));
    float e0 = expf(a[0] - mx), e1 = expf(a[1] - mx), e2 = expf(a[2] - mx);
    float s = e0 + e1 + e2;
    wgt[0 * 128 + t] = e0 / s;
    wgt[1 * 128 + t] = e1 / s;
    wgt[2 * 128 + t] = e2 / s;
}

// ---------------- combine: out = (f1+b1)*w0 + (f2+b2)*w1 + (f3+b3)*w2 ----------------
// f1 = d_out (f32, in place); f2/f3 bf16x2 tables

__global__ __launch_bounds__(256) void combine_kernel(float* __restrict__ out,
                                                      const unsigned* __restrict__ f2,
                                                      const unsigned* __restrict__ f3,
                                                      const float* __restrict__ b1,
                                                      const float* __restrict__ b2,
                                                      const float* __restrict__ b3,
                                                      const float* __restrict__ wgt) {
    const int total = N_NODES * 32;  // float4 count
    int idx0 = blockIdx.x * blockDim.x + threadIdx.x;
    int stride = gridDim.x * blockDim.x;
    int qb = idx0 & 31;
    const float4* wgt4 = (const float4*)wgt;
    float4 W0 = wgt4[qb], W1 = wgt4[32 + qb], W2 = wgt4[64 + qb];
    float4 B1 = ((const float4*)b1)[qb];
    float4 B2 = ((const float4*)b2)[qb];
    float4 B3 = ((const float4*)b3)[qb];
    for (int idx = idx0; idx < total; idx += stride) {
        float4 v1 = ((const float4*)out)[idx];
        uint2 u2 = ((const uint2*)f2)[idx];
        uint2 u3 = ((const uint2*)f3)[idx];
        float4 o;
        o.x = (v1.x + B1.x) * W0.x + (bf_lo(u2.x) + B2.x) * W1.x + (bf_lo(u3.x) + B3.x) * W2.x;
        o.y = (v1.y + B1.y) * W0.y + (bf_hi(u2.x) + B2.y) * W1.y + (bf_hi(u3.x) + B3.y) * W2.y;
        o.z = (v1.z + B1.z) * W0.z + (bf_lo(u2.y) + B2.z) * W1.z + (bf_lo(u3.y) + B3.z) * W2.z;
        o.w = (v1.w + B1.w) * W0.w + (bf_hi(u2.y) + B2.w) * W1.w + (bf_hi(u3.y) + B3.w) * W2.w;
        ((float4*)out)[idx] = o;
    }
}

// ---------------- launch ----------------

extern "C" void kernel_launch(void* const* d_in, const int* in_sizes, int n_in,
                              void* d_out, int out_size, void* d_ws, size_t ws_size,
                              hipStream_t stream) {
    const float* F    = (const float*)d_in[0];
    const int*   erow = (const int*)d_in[1];
    const int*   ecol = (const int*)d_in[2];
    const float* eval_ = (const float*)d_in[3];
    const float* w1 = (const float*)d_in[4];  const float* b1 = (const float*)d_in[5];
    const float* w2 = (const float*)d_in[6];  const float* b2 = (const float*)d_in[7];
    const float* w3 = (const float*)d_in[8];  const float* b3 = (const float*)d_in[9];
    const float* fc1w = (const float*)d_in[10]; const float* fc1b = (const float*)d_in[11];
    const float* fc2w = (const float*)d_in[12]; const float* fc2b = (const float*)d_in[13];
    float* out = (float*)d_out;

    char* ws = (char*)d_ws;
    size_t off = 0;
    auto alloc = [&](size_t bytes) -> void* {
        off = (off + 255) & ~(size_t)255;
        void* p = ws + off;
        off += bytes;
        return p;
    };
    // T1: [h3|h2|h1] 192 dwords/row (38.4 MB). f2bf/f3bf alias into T1's space after S1.
    unsigned* T1   = (unsigned*)alloc((size_t)N_NODES * 192 * 4);
    unsigned* T2   = (unsigned*)alloc((size_t)N_NODES * 128 * 4);   // [u3|v2] 25.6 MB
    unsigned* T3   = (unsigned*)alloc((size_t)N_NODES * 64 * 4);    // [w3]   12.8 MB
    unsigned* ep   = (unsigned*)alloc((size_t)N_EDGES * 4);         // packed edges 3.2 MB
    int*   counts  = (int*)alloc((size_t)N_NODES * sizeof(int));
    int*   offs    = (int*)alloc((size_t)N_NODES * sizeof(int));
    int*   cursor  = (int*)alloc((size_t)N_NODES * sizeof(int));
    int*   bsum    = (int*)alloc(64 * sizeof(int));
    float* csum    = (float*)alloc(8 * 3 * 128 * sizeof(float));
    float* wgt     = (float*)alloc(3 * 128 * sizeof(float));
    unsigned* f2bf = T1;                               // 12.8 MB, T1 dead after S1
    unsigned* f3bf = T1 + (size_t)N_NODES * 64;        // next 12.8 MB

    const int nScanBlocks = (N_NODES + 1023) / 1024;  // 49

    // --- CSR build ---
    hipMemsetAsync(counts, 0, (size_t)N_NODES * sizeof(int), stream);
    count_kernel<<<(N_EDGES + 255) / 256, 256, 0, stream>>>(erow, counts, N_EDGES);
    scanA_kernel<<<nScanBlocks, 1024, 0, stream>>>(counts, offs, bsum, N_NODES);
    scanB_kernel<<<1, 64, 0, stream>>>(bsum, nScanBlocks);
    scanC_kernel<<<nScanBlocks, 1024, 0, stream>>>(offs, cursor, bsum, N_NODES);
    scatter_kernel<<<(N_EDGES + 255) / 256, 256, 0, stream>>>(erow, ecol, eval_, cursor, ep, N_EDGES);
    hipMemsetAsync(csum, 0, 8 * 3 * 128 * sizeof(float), stream);

    // --- fused 3-branch GEMM: T1 = [tanh(Fw3)|tanh(Fw2)|tanh(Fw1)] bf16 ---
    gemm_tanh3_kernel<<<(N_NODES + 31) / 32, 256, 0, stream>>>(F, w3, w2, w1, T1, N_NODES);

    const int spmmGrid = N_NODES / 8;  // 6250, exact

    // --- S1: A * [h3|h2|h1] -> [u3|v2] (T2 bf16) + f1 (d_out f32, colsum slot 0) ---
    spmm_stage_kernel<3, true><<<spmmGrid, 512, 0, stream>>>(offs, counts, ep, T1, T2,
                                                             nullptr, (float2*)out, csum + 0 * 128);
    // --- S2: A * [u3|v2] -> [w3] (T3 bf16) + f2 (f2bf bf16, colsum slot 1) ---
    spmm_stage_kernel<2, false><<<spmmGrid, 512, 0, stream>>>(offs, counts, ep, T2, T3,
                                                              f2bf, nullptr, csum + 1 * 128);
    // --- S3: A * [w3] -> f3 (f3bf bf16, colsum slot 2) ---
    spmm_stage_kernel<1, false><<<spmmGrid, 512, 0, stream>>>(offs, counts, ep, T3, nullptr,
                                                              f3bf, nullptr, csum + 2 * 128);

    // --- FC + softmax ---
    fc_softmax_kernel<<<1, 128, 0, stream>>>(csum, b1, b2, b3, fc1w, fc1b, fc2w, fc2b, wgt);

    // --- weighted combine (in place on d_out) ---
    combine_kernel<<<2048, 256, 0, stream>>>(out, f2bf, f3bf, b1, b2, b3, wgt);
}

// Round 4
// 345.356 us; speedup vs baseline: 1.9781x; 1.2656x over previous
//
#include <hip/hip_runtime.h>
#include <cstdint>

#define N_NODES 50000
#define N_EDGES 800000
#define DIM 128
#define EPCAP 64

typedef _Float16 half8 __attribute__((ext_vector_type(8)));
typedef float f32x4 __attribute__((ext_vector_type(4)));

// ---------------- f16 helpers ----------------

__device__ inline unsigned pack_half2(float lo, float hi) {
    union { _Float16 h[2]; unsigned u; } cv;
    cv.h[0] = (_Float16)lo; cv.h[1] = (_Float16)hi;
    return cv.u;
}
__device__ inline float h_lo(unsigned u) {
    union { unsigned u; _Float16 h[2]; } cv; cv.u = u; return (float)cv.h[0];
}
__device__ inline float h_hi(unsigned u) {
    union { unsigned u; _Float16 h[2]; } cv; cv.u = u; return (float)cv.h[1];
}

// ---------------- direct scatter: ep[row*64 + slot] = (f16val<<16 | col) ----------------

__global__ void scatter_kernel(const int* __restrict__ rows, const int* __restrict__ cols,
                               const float* __restrict__ vals, int* __restrict__ cnt,
                               unsigned* __restrict__ ep, int ne) {
    int e = blockIdx.x * blockDim.x + threadIdx.x;
    if (e < ne) {
        int r = rows[e];
        int p = atomicAdd(&cnt[r], 1);
        union { _Float16 h; unsigned short s; } cv; cv.h = (_Float16)vals[e];
        if (p < EPCAP) ep[(size_t)r * EPCAP + p] = ((unsigned)cv.s << 16) | (unsigned)cols[e];
    }
}

// ---------------- W prep: f32 [d][j] -> f16 [branch][j][d] ----------------

__global__ __launch_bounds__(256) void wprep_kernel(const float* __restrict__ w3,
                                                    const float* __restrict__ w2,
                                                    const float* __restrict__ w1,
                                                    _Float16* __restrict__ Wt) {
    const float* W = (blockIdx.x == 0) ? w3 : (blockIdx.x == 1) ? w2 : w1;
    _Float16* O = Wt + (size_t)blockIdx.x * 16384;
    int tid = threadIdx.x;
    for (int i = tid; i < 16384; i += 256) {
        int j = i >> 7, d = i & 127;
        O[j * 128 + d] = (_Float16)W[d * 128 + j];
    }
}

// ---------------- fused 3-branch MFMA GEMM: T1[row][b*64+g] = half2(tanh(C)[g], tanh(C)[g+64]) ----

__global__ __launch_bounds__(256) void gemm_mfma3_kernel(const float* __restrict__ F,
                                                         const _Float16* __restrict__ Wt,
                                                         unsigned* __restrict__ T1, int nrows) {
    __shared__ _Float16 Fs[64 * 128];    // 16 KiB, XOR-swizzled rows
    __shared__ _Float16 Ws[128 * 128];   // 32 KiB, [j][k] XOR-swizzled
    int tid = threadIdx.x;
    int lane = tid & 63, wv = tid >> 6;
    int c = lane & 15, g = lane >> 4;
    int rowbase = blockIdx.x * 64;

    // stage F rows (f32 -> f16), swizzle byte ^= (row&15)<<4
    for (int i = tid; i < 4096; i += 256) {
        int r = i >> 6;
        int row = rowbase + r; if (row >= nrows) row = nrows - 1;
        float2 fv = ((const float2*)F)[(size_t)row * 64 + (i & 63)];
        *(unsigned*)((char*)Fs + ((i * 4) ^ ((r & 15) << 4))) = pack_half2(fv.x, fv.y);
    }
    __syncthreads();

    // A fragments: row = wv*16 + c, k = ks*32 + g*8 .. +7 (held for all 3 branches)
    half8 afr[4];
    #pragma unroll
    for (int ks = 0; ks < 4; ++ks) {
        int off = (((wv * 16 + c) * 128 + ks * 32 + g * 8) * 2) ^ (c << 4);
        afr[ks] = *(const half8*)((const char*)Fs + off);
    }

    for (int b = 0; b < 3; ++b) {
        const unsigned* WtU = (const unsigned*)(Wt + (size_t)b * 16384);
        for (int i = tid; i < 8192; i += 256) {
            int j = i >> 6;
            *(unsigned*)((char*)Ws + ((i * 4) ^ ((j & 15) << 4))) = WtU[i];
        }
        __syncthreads();

        f32x4 zero = {0.f, 0.f, 0.f, 0.f};
        f32x4 acc[8];
        #pragma unroll
        for (int t = 0; t < 8; ++t) acc[t] = zero;

        #pragma unroll
        for (int ks = 0; ks < 4; ++ks) {
            #pragma unroll
            for (int t = 0; t < 8; ++t) {
                int j = t * 16 + c;
                int off = ((j * 128 + ks * 32 + g * 8) * 2) ^ ((j & 15) << 4);
                half8 bfr = *(const half8*)((const char*)Ws + off);
                acc[t] = __builtin_amdgcn_mfma_f32_16x16x32_f16(afr[ks], bfr, acc[t], 0, 0, 0);
            }
        }

        // epilogue: lane holds cols j=t*16+c (lo) and j+64 (hi, tile t+4), rows g*4+r
        #pragma unroll
        for (int t = 0; t < 4; ++t) {
            int j = t * 16 + c;
            #pragma unroll
            for (int r = 0; r < 4; ++r) {
                int row = rowbase + wv * 16 + g * 4 + r;
                if (row < nrows)
                    T1[(size_t)row * 192 + b * 64 + j] =
                        pack_half2(tanhf(acc[t][r]), tanhf(acc[t + 4][r]));
            }
        }
        __syncthreads();  // MFMA reads done before next branch overwrites Ws
    }
}

// ---------------- batched SpMM stage (f16 tables, dim-split layout) ----------------
// x: NCHUNK*64 dwords/row. Chunks 0..NCHUNK-2 -> ob0. Final chunk -> f32 true-layout
// (fout) if F32FINAL else f16 dword (obf); final chunk also column-summed into csum.

template <int NCHUNK, bool F32FINAL>
__global__ __launch_bounds__(512) void spmm_stage_kernel(const int* __restrict__ cnts,
                                                         const unsigned* __restrict__ ep,
                                                         const unsigned* __restrict__ x,
                                                         unsigned* __restrict__ ob0,
                                                         unsigned* __restrict__ obf,
                                                         float* __restrict__ fout,
                                                         float* __restrict__ csum) {
    __shared__ float cs[128];
    int tid = threadIdx.x;
    if (tid < 128) cs[tid] = 0.f;
    __syncthreads();

    int row = blockIdx.x * 8 + (tid >> 6);
    int lane = tid & 63;
    int n = __builtin_amdgcn_readfirstlane(cnts[row]);
    n = n < EPCAP ? n : EPCAP;
    const unsigned* e0 = ep + (size_t)row * EPCAP;

    float ax[NCHUNK], ay[NCHUNK];
    #pragma unroll
    for (int cc = 0; cc < NCHUNK; ++cc) { ax[cc] = 0.f; ay[cc] = 0.f; }

    const unsigned* xl = x + lane;
    constexpr int U = (NCHUNK == 1) ? 8 : 4;
    int i = 0;
    for (; i + U <= n; i += U) {
        unsigned p[U];
        #pragma unroll
        for (int u = 0; u < U; ++u) p[u] = e0[i + u];
        unsigned gx[U][NCHUNK];
        #pragma unroll
        for (int u = 0; u < U; ++u) {
            unsigned b = (p[u] & 0xFFFFu) * (unsigned)(NCHUNK * 64);
            #pragma unroll
            for (int cc = 0; cc < NCHUNK; ++cc) gx[u][cc] = xl[b + cc * 64];
        }
        #pragma unroll
        for (int u = 0; u < U; ++u) {
            union { unsigned short s; _Float16 h; } cu; cu.s = (unsigned short)(p[u] >> 16);
            float v = (float)cu.h;
            #pragma unroll
            for (int cc = 0; cc < NCHUNK; ++cc) {
                ax[cc] += v * h_lo(gx[u][cc]);
                ay[cc] += v * h_hi(gx[u][cc]);
            }
        }
    }
    for (; i < n; ++i) {
        unsigned p = e0[i];
        unsigned b = (p & 0xFFFFu) * (unsigned)(NCHUNK * 64);
        union { unsigned short s; _Float16 h; } cu; cu.s = (unsigned short)(p >> 16);
        float v = (float)cu.h;
        #pragma unroll
        for (int cc = 0; cc < NCHUNK; ++cc) {
            unsigned gg = xl[b + cc * 64];
            ax[cc] += v * h_lo(gg);
            ay[cc] += v * h_hi(gg);
        }
    }

    #pragma unroll
    for (int cc = 0; cc < NCHUNK - 1; ++cc)
        ob0[(size_t)row * ((NCHUNK - 1) * 64) + cc * 64 + lane] = pack_half2(ax[cc], ay[cc]);

    float fx = ax[NCHUNK - 1], fy = ay[NCHUNK - 1];
    if (F32FINAL) {
        // true layout: lane's dims are (lane, lane+64)
        fout[(size_t)row * 128 + lane] = fx;
        fout[(size_t)row * 128 + 64 + lane] = fy;
    } else {
        obf[(size_t)row * 64 + lane] = pack_half2(fx, fy);
    }
    atomicAdd(&cs[2 * lane + 0], fx);   // slot 2g   <-> dim g
    atomicAdd(&cs[2 * lane + 1], fy);   // slot 2g+1 <-> dim g+64
    __syncthreads();
    if (tid < 128) atomicAdd(&csum[(blockIdx.x & 7) * 384 + tid], cs[tid]);
}

// ---------------- FC + softmax over order (slot remap for dim-split csum) ----------------

__global__ __launch_bounds__(128) void fc_softmax_kernel(const float* __restrict__ csum,
                                                         const float* __restrict__ b1,
                                                         const float* __restrict__ b2,
                                                         const float* __restrict__ b3,
                                                         const float* __restrict__ fc1w,
                                                         const float* __restrict__ fc1b,
                                                         const float* __restrict__ fc2w,
                                                         const float* __restrict__ fc2b,
                                                         float* __restrict__ wgt) {
    __shared__ float m[3][128];
    __shared__ float r[3][32];
    int t = threadIdx.x;
    const float inv = 1.0f / (float)N_NODES;
    int slot = (t < 64) ? (2 * t) : (2 * (t - 64) + 1);
    #pragma unroll
    for (int k = 0; k < 3; ++k) {
        float s = 0.f;
        #pragma unroll
        for (int rep = 0; rep < 8; ++rep) s += csum[rep * 384 + k * 128 + slot];
        const float* bk = (k == 0) ? b1 : (k == 1) ? b2 : b3;
        m[k][t] = s * inv + bk[t];
    }
    __syncthreads();
    if (t < 96) {
        int k = t >> 5, j = t & 31;
        float acc = fc1b[j];
        for (int d = 0; d < 128; ++d) acc += m[k][d] * fc1w[d * 32 + j];
        r[k][j] = fmaxf(acc, 0.f);
    }
    __syncthreads();
    float a[3];
    #pragma unroll
    for (int k = 0; k < 3; ++k) {
        float acc = fc2b[t];
        for (int j = 0; j < 32; ++j) acc += r[k][j] * fc2w[j * 128 + t];
        a[k] = acc;
    }
    float mx = fmaxf(a[0], fmaxf(a[1], a[2]));
    float e0 = expf(a[0] - mx), e1 = expf(a[1] - mx), e2 = expf(a[2] - mx);
    float s = e0 + e1 + e2;
    wgt[0 * 128 + t] = e0 / s;
    wgt[1 * 128 + t] = e1 / s;
    wgt[2 * 128 + t] = e2 / s;
}

// ---------------- combine: out = (f1+b1)*w0 + (f2+b2)*w1 + (f3+b3)*w2 ----------------
// f1 = d_out true layout f32; f2/f3 dim-split f16 dwords (dword g = dims g, g+64)

__global__ __launch_bounds__(256) void combine_kernel(float* __restrict__ out,
                                                      const unsigned* __restrict__ f2,
                                                      const unsigned* __restrict__ f3,
                                                      const float* __restrict__ b1,
                                                      const float* __restrict__ b2,
                                                      const float* __restrict__ b3,
                                                      const float* __restrict__ wgt) {
    const int total = N_NODES * 32;  // float4 count
    int idx0 = blockIdx.x * blockDim.x + threadIdx.x;
    int stride = gridDim.x * blockDim.x;  // multiple of 32
    int qb = idx0 & 31;                    // float4 slot in row: dims 4qb..4qb+3
    float4 W0 = ((const float4*)wgt)[qb];
    float4 W1 = ((const float4*)wgt)[32 + qb];
    float4 W2 = ((const float4*)wgt)[64 + qb];
    float4 B1 = ((const float4*)b1)[qb];
    float4 B2 = ((const float4*)b2)[qb];
    float4 B3 = ((const float4*)b3)[qb];
    bool hi = qb >= 16;
    int qm = qb & 15;
    for (int idx = idx0; idx < total; idx += stride) {
        int row = idx >> 5;
        float4 v1 = ((const float4*)out)[idx];
        uint4 u2 = ((const uint4*)f2)[row * 16 + qm];
        uint4 u3 = ((const uint4*)f3)[row * 16 + qm];
        float f2x = hi ? h_hi(u2.x) : h_lo(u2.x);
        float f2y = hi ? h_hi(u2.y) : h_lo(u2.y);
        float f2z = hi ? h_hi(u2.z) : h_lo(u2.z);
        float f2w = hi ? h_hi(u2.w) : h_lo(u2.w);
        float f3x = hi ? h_hi(u3.x) : h_lo(u3.x);
        float f3y = hi ? h_hi(u3.y) : h_lo(u3.y);
        float f3z = hi ? h_hi(u3.z) : h_lo(u3.z);
        float f3w = hi ? h_hi(u3.w) : h_lo(u3.w);
        float4 o;
        o.x = (v1.x + B1.x) * W0.x + (f2x + B2.x) * W1.x + (f3x + B3.x) * W2.x;
        o.y = (v1.y + B1.y) * W0.y + (f2y + B2.y) * W1.y + (f3y + B3.y) * W2.y;
        o.z = (v1.z + B1.z) * W0.z + (f2z + B2.z) * W1.z + (f3z + B3.z) * W2.z;
        o.w = (v1.w + B1.w) * W0.w + (f2w + B2.w) * W1.w + (f3w + B3.w) * W2.w;
        ((float4*)out)[idx] = o;
    }
}

// ---------------- launch ----------------

extern "C" void kernel_launch(void* const* d_in, const int* in_sizes, int n_in,
                              void* d_out, int out_size, void* d_ws, size_t ws_size,
                              hipStream_t stream) {
    const float* F    = (const float*)d_in[0];
    const int*   erow = (const int*)d_in[1];
    const int*   ecol = (const int*)d_in[2];
    const float* eval_ = (const float*)d_in[3];
    const float* w1 = (const float*)d_in[4];  const float* b1 = (const float*)d_in[5];
    const float* w2 = (const float*)d_in[6];  const float* b2 = (const float*)d_in[7];
    const float* w3 = (const float*)d_in[8];  const float* b3 = (const float*)d_in[9];
    const float* fc1w = (const float*)d_in[10]; const float* fc1b = (const float*)d_in[11];
    const float* fc2w = (const float*)d_in[12]; const float* fc2b = (const float*)d_in[13];
    float* out = (float*)d_out;

    char* ws = (char*)d_ws;
    size_t off = 0;
    auto alloc = [&](size_t bytes) -> void* {
        off = (off + 255) & ~(size_t)255;
        void* p = ws + off;
        off += bytes;
        return p;
    };
    unsigned* T1   = (unsigned*)alloc((size_t)N_NODES * 192 * 4);       // 38.4 MB [h3|h2|h1]
    unsigned* T2   = (unsigned*)alloc((size_t)N_NODES * 128 * 4);       // 25.6 MB [u3|v2]
    unsigned* T3   = (unsigned*)alloc((size_t)N_NODES * 64 * 4);        // 12.8 MB [w3]
    unsigned* ep   = (unsigned*)alloc((size_t)N_NODES * EPCAP * 4);     // 12.8 MB edge buckets
    int*   counts  = (int*)alloc((size_t)N_NODES * sizeof(int));
    _Float16* Wt   = (_Float16*)alloc(3 * 16384 * sizeof(_Float16));    // 96 KB
    float* csum    = (float*)alloc(8 * 3 * 128 * sizeof(float));
    float* wgt     = (float*)alloc(3 * 128 * sizeof(float));
    unsigned* f2bf = T1;                               // alias: T1 dead after S1
    unsigned* f3bf = T1 + (size_t)N_NODES * 64;

    hipMemsetAsync(counts, 0, (size_t)N_NODES * sizeof(int), stream);
    hipMemsetAsync(csum, 0, 8 * 3 * 128 * sizeof(float), stream);

    scatter_kernel<<<(N_EDGES + 255) / 256, 256, 0, stream>>>(erow, ecol, eval_, counts, ep, N_EDGES);
    wprep_kernel<<<3, 256, 0, stream>>>(w3, w2, w1, Wt);
    gemm_mfma3_kernel<<<(N_NODES + 63) / 64, 256, 0, stream>>>(F, Wt, T1, N_NODES);

    const int spmmGrid = N_NODES / 8;  // 6250, exact

    // S1: A*[h3|h2|h1] -> [u3|v2](T2) + f1 (d_out f32 true layout, csum slot 0)
    spmm_stage_kernel<3, true><<<spmmGrid, 512, 0, stream>>>(counts, ep, T1, T2,
                                                             nullptr, out, csum + 0 * 128);
    // S2: A*[u3|v2] -> [w3](T3) + f2 (f2bf f16, csum slot 1)
    spmm_stage_kernel<2, false><<<spmmGrid, 512, 0, stream>>>(counts, ep, T2, T3,
                                                              f2bf, nullptr, csum + 1 * 128);
    // S3: A*[w3] -> f3 (f3bf f16, csum slot 2)
    spmm_stage_kernel<1, false><<<spmmGrid, 512, 0, stream>>>(counts, ep, T3, nullptr,
                                                              f3bf, nullptr, csum + 2 * 128);

    fc_softmax_kernel<<<1, 128, 0, stream>>>(csum, b1, b2, b3, fc1w, fc1b, fc2w, fc2b, wgt);
    combine_kernel<<<2048, 256, 0, stream>>>(out, f2bf, f3bf, b1, b2, b3, wgt);
}